// Round 17
// baseline (130.674 us; speedup 1.0000x reference)
//
#include <hip/hip_runtime.h>
#include <hip/hip_bf16.h>
#include <stdint.h>

// VSN: B=16,T=256 -> NTOK=4096 tokens, V=64 vars, H=256 hidden.
#define NTOK 4096
#define NV 64
#define NH 256
#define LN_EPS 1e-5f

typedef __attribute__((ext_vector_type(8))) short short8;
typedef __attribute__((ext_vector_type(4))) float f32x4;
typedef __attribute__((ext_vector_type(2))) float f32x2;   // true vector: safe in asm "v"
typedef __attribute__((ext_vector_type(4))) uint32_t u32x4;

__device__ __forceinline__ f32x2 mk2(float a, float b) {
    f32x2 r; r.x = a; r.y = b; return r;
}
__device__ __forceinline__ unsigned short f32_to_bf16(float f) {
    uint32_t u = __builtin_bit_cast(uint32_t, f);
    return (unsigned short)((u + 0x7FFFu + ((u >> 16) & 1u)) >> 16);  // RNE
}
__device__ __forceinline__ float fsigmoid(float z) { return 1.0f / (1.0f + __expf(-z)); }
__device__ __forceinline__ float felu(float z) { return z > 0.0f ? z : (__expf(z) - 1.0f); }
// packed f32 dual-rate math (VOP3P, CDNA3+) on genuine ext-vector pairs
__device__ __forceinline__ f32x2 pk_fma(f32x2 a, f32x2 b, f32x2 c) {
    f32x2 d;
    asm("v_pk_fma_f32 %0, %1, %2, %3" : "=v"(d) : "v"(a), "v"(b), "v"(c));
    return d;
}
__device__ __forceinline__ f32x2 pk_add(f32x2 a, f32x2 b) {
    f32x2 d;
    asm("v_pk_add_f32 %0, %1, %2" : "=v"(d) : "v"(a), "v"(b));
    return d;
}
__device__ __forceinline__ f32x2 pk_mul(f32x2 a, f32x2 b) {
    f32x2 d;
    asm("v_pk_mul_f32 %0, %1, %2" : "=v"(d) : "v"(a), "v"(b));
    return d;
}
__device__ __forceinline__ uint32_t cvtpk_bf16(float lo, float hi) {
    uint32_t r;
    asm("v_cvt_pk_bf16_f32 %0, %1, %2" : "=v"(r) : "v"(lo), "v"(hi));
    return r;
}
__device__ __forceinline__ void gload16(const void* g, void* l) {
    __builtin_amdgcn_global_load_lds(
        (const __attribute__((address_space(1))) uint32_t*)g,
        (__attribute__((address_space(3))) uint32_t*)l, 16, 0, 0);
}

// ---------------- Kernel PRE: fused {W2 transpose, weight GRN, Wg/bg scale} -------
// Blocks [0,4096): W2 [v][h][o] f32 -> W2T [v][o][h] bf16 (one 32x32 tile each).
// Blocks [4096,5120): per-token weight-network GRN + softmax -> wgt[tok][v].
// Blocks [5120,5136): scale Wg,bg by -log2(e) into Wg2,bg2.
__global__ __launch_bounds__(256) void k_pre(
    const float* __restrict__ W2, unsigned short* __restrict__ W2T,
    const float* __restrict__ x,
    const float* __restrict__ nW1, const float* __restrict__ nb1,
    const float* __restrict__ nW2, const float* __restrict__ nb2,
    const float* __restrict__ nWg, const float* __restrict__ nbg,
    const float* __restrict__ ng,  const float* __restrict__ nbe,
    float* __restrict__ wout_buf,
    const float* __restrict__ Wg, const float* __restrict__ bg,
    float* __restrict__ Wg2, float* __restrict__ bg2) {
    __shared__ float tile[32][33];
    const int bid = blockIdx.x;
    if (bid < 4096) {
        // ---- W2 -> W2T (bf16, transposed) ----
        const int v  = bid >> 6;
        const int t  = bid & 63;
        const int h0 = (t & 7) * 32;
        const int o0 = (t >> 3) * 32;
        const int r  = threadIdx.x >> 3;
        const int c4 = (threadIdx.x & 7) * 4;
        const float4 d = *(const float4*)(W2 + ((size_t)v * NH + h0 + r) * NH + o0 + c4);
        tile[r][c4 + 0] = d.x; tile[r][c4 + 1] = d.y;
        tile[r][c4 + 2] = d.z; tile[r][c4 + 3] = d.w;
        __syncthreads();
        ushort4 o;
        o.x = f32_to_bf16(tile[c4 + 0][r]);
        o.y = f32_to_bf16(tile[c4 + 1][r]);
        o.z = f32_to_bf16(tile[c4 + 2][r]);
        o.w = f32_to_bf16(tile[c4 + 3][r]);
        *(ushort4*)(W2T + ((size_t)v * NH + o0 + r) * NH + h0 + c4) = o;
        return;
    }
    if (bid >= 4096 + NTOK / 4) {
        // ---- Wg/bg scale ----
        const int i = (bid - 4096 - NTOK / 4) * 256 + threadIdx.x;  // 4096 float4s
        const float cc = -1.44269504f;
        const float4 a = ((const float4*)Wg)[i];
        const float4 b = ((const float4*)bg)[i];
        ((float4*)Wg2)[i] = float4{a.x * cc, a.y * cc, a.z * cc, a.w * cc};
        ((float4*)bg2)[i] = float4{b.x * cc, b.y * cc, b.z * cc, b.w * cc};
        return;
    }
    // ---- weight-network GRN + softmax ----
    const int wv = threadIdx.x >> 6;
    const int lane = threadIdx.x & 63;
    const int tok = (bid - 4096) * 4 + wv;
    const float xv = x[(size_t)tok * NV + lane];
    float acc1 = nb1[lane], accg = nbg[lane];
#pragma unroll 8
    for (int k = 0; k < 64; ++k) {
        const float xk = __shfl(xv, k);
        acc1 = fmaf(xk, nW1[k * 64 + lane], acc1);
        accg = fmaf(xk, nWg[k * 64 + lane], accg);
    }
    const float h  = felu(acc1);
    const float wg = fsigmoid(accg);
    float acc2 = nb2[lane];
#pragma unroll 8
    for (int k = 0; k < 64; ++k) {
        const float hk = __shfl(h, k);
        acc2 = fmaf(hk, nW2[k * 64 + lane], acc2);
    }
    const float pre = xv + wg * acc2;
    float s = pre;
#pragma unroll
    for (int m = 32; m >= 1; m >>= 1) s += __shfl_xor(s, m);
    const float mu = s * (1.0f / 64.0f);
    const float dd = pre - mu;
    float s2 = dd * dd;
#pragma unroll
    for (int m = 32; m >= 1; m >>= 1) s2 += __shfl_xor(s2, m);
    const float inv = rsqrtf(s2 * (1.0f / 64.0f) + LN_EPS);
    const float wln = dd * inv * ng[lane] + nbe[lane];
    float mx = wln;
#pragma unroll
    for (int m = 32; m >= 1; m >>= 1) mx = fmaxf(mx, __shfl_xor(mx, m));
    const float e = __expf(wln - mx);
    float se = e;
#pragma unroll
    for (int m = 32; m >= 1; m >>= 1) se += __shfl_xor(se, m);
    wout_buf[(size_t)tok * NV + lane] = e / se;
}

__device__ __forceinline__ const float* row_ptr(int r, const float* W1, const float* b1,
                                                const float* Wg, const float* bg,
                                                const float* Ws, const float* bs,
                                                const float* b2, const float* g1,
                                                const float* be1) {
    switch (r) {
        case 0: return W1; case 1: return b1; case 2: return Wg; case 3: return bg;
        case 4: return Ws; case 5: return bs; case 6: return b2; case 7: return g1;
        default: return be1;
    }
}

// ---------------- Kernel C: r15 best-passing structure (byte-identical) -----------
// grid 512 (bid&7 = vgroup/XCD; bid>>3 = 64-token tile). 256 thr = 4 waves; each
// wave = 16 tokens x ALL 256 cols. Per-phase sync: s_waitcnt vmcnt(4) + raw
// s_barrier (3-buf B ring staged 2 phases ahead). Arithmetic: v_pk_* on f32x2
// ext-vectors, exp2-native sigmoid (pre-scaled Wg2/bg2), v_cvt_pk_bf16 A-pack.
// Tail: partials stored as bf16 (halves partial-path HBM traffic).
__global__ __launch_bounds__(256, 2) void k_main(
    const float* __restrict__ x, const unsigned short* __restrict__ W2T,
    const float* __restrict__ W1, const float* __restrict__ b1,
    const float* __restrict__ Wg2, const float* __restrict__ bg2,
    const float* __restrict__ Ws, const float* __restrict__ bs,
    const float* __restrict__ b2, const float* __restrict__ g1,
    const float* __restrict__ be1, const float* __restrict__ wgts,
    unsigned short* __restrict__ partials16,  // [8][NTOK][NH] bf16 or nullptr
    float* __restrict__ outacc) {             // atomic fallback
    __shared__ u32x4 sB[3][1024];     // 3 x 16KB B K-step panel ring, slot-swizzled
    __shared__ float sRB[2][9][256];  // 2 x {W1,b1,Wg2,bg2,Ws,bs,b2,g1,be1}
    __shared__ float sX[64][9];       // [tok][var] (+pad)
    __shared__ float sW[64][9];

    const int tid  = threadIdx.x;
    const int wid  = tid >> 6, lane = tid & 63;  // wid = token-group
    const int c    = lane & 15, kg = lane >> 4;
    const int bid  = blockIdx.x;
    const int vg   = bid & 7, tt = bid >> 3;
    const int t0   = tt * 64, vbase = vg * 8;

    const float* r0p = row_ptr(2 * wid,     W1, b1, Wg2, bg2, Ws, bs, b2, g1, be1);
    const float* r1p = row_ptr(2 * wid + 1, W1, b1, Wg2, bg2, Ws, bs, b2, g1, be1);

    // per-thread B-stage constants (4 chunks): idx -> (o, slot) -> src/dst offsets
    int bsrc[4], bdst[4];
#pragma unroll
    for (int q = 0; q < 4; ++q) {
        const int idx = wid * 256 + q * 64 + lane;
        const int o = idx >> 2, sl = idx & 3;
        const int s = (sl - (o >> 1)) & 3;
        bsrc[q] = o * NH + s * 8;   // element offset within the var's W2T
        bdst[q] = idx * 16;         // byte offset within panel
    }

#define STAGE_B(vt, kt, buf)                                                     \
    do {                                                                         \
        const unsigned short* Wsrc_ = W2T + (size_t)(vt) * (NH * NH) + (kt) * 32;\
        char* dst_ = (char*)sB[buf];                                             \
        gload16(Wsrc_ + bsrc[0], dst_ + bdst[0]);                                \
        gload16(Wsrc_ + bsrc[1], dst_ + bdst[1]);                                \
        gload16(Wsrc_ + bsrc[2], dst_ + bdst[2]);                                \
        gload16(Wsrc_ + bsrc[3], dst_ + bdst[3]);                                \
    } while (0)

#define STAGE_ROWS(vt, rbuf)                                                     \
    do {                                                                         \
        gload16(r0p + (size_t)(vt) * NH + lane * 4,                              \
                (char*)sRB[rbuf] + (2 * wid) * 1024);                            \
        gload16(r1p + (size_t)(vt) * NH + lane * 4,                              \
                (char*)sRB[rbuf] + (2 * wid + 1) * 1024);                        \
        if (wid == 0)                                                            \
            gload16(be1 + (size_t)(vt) * NH + lane * 4,                          \
                    (char*)sRB[rbuf] + 8 * 1024);                                \
    } while (0)

    // ---- prologue: stage (v0,ks0)->sB0, (v0,ks1)->sB1, rows v0; fill sX/sW ----
    STAGE_B(vbase, 0, 0);
    STAGE_B(vbase, 1, 1);
    STAGE_ROWS(vbase, 0);
#pragma unroll
    for (int e = 0; e < 2; ++e) {
        const int ee = tid + e * 256;
        const int row = ee >> 3, cc = ee & 7;
        sX[row][cc] = x[(size_t)(t0 + row) * NV + vbase + cc];
        sW[row][cc] = wgts[(size_t)(t0 + row) * NV + vbase + cc];
    }
    __syncthreads();   // one full drain (prologue only)

    // b128 B-frag read base: row o = f*16+c, slot rotated -> balanced banks
    const int rdbase = c * 64 + (((kg + (c >> 1)) & 3) << 4);
    const f32x4 fzero = {0.f, 0.f, 0.f, 0.f};
    const f32x2 one2 = {1.0f, 1.0f};

    f32x4 wacc[16];
#pragma unroll
    for (int f = 0; f < 16; ++f) wacc[f] = fzero;

    int cur = 0;   // sB ring position for the phase being consumed

#pragma unroll 1
    for (int vi = 0; vi < 8; ++vi) {
        const int rcur = vi & 1;
        const float xv = sX[wid * 16 + c][vi];
        const f32x2 xv2 = {xv, xv};

        f32x4 acc[16];
#pragma unroll
        for (int f = 0; f < 16; ++f) acc[f] = fzero;

#pragma unroll 1
        for (int ks = 0; ks < 8; ++ks) {
            // ---- phase top: counted wait + raw barrier (no vmcnt(0) drain) ----
            asm volatile("s_waitcnt vmcnt(4)" ::: "memory");
            __builtin_amdgcn_sched_barrier(0);
            __builtin_amdgcn_s_barrier();

            // -- A-frag gen (one 16x32 tile per wave): pk-fma pairs + cvt_pk --
            const int k0 = ks * 32 + kg * 8;
            const float4 wA = *(const float4*)&sRB[rcur][0][k0];
            const float4 wB = *(const float4*)&sRB[rcur][0][k0 + 4];
            const float4 bA = *(const float4*)&sRB[rcur][1][k0];
            const float4 bB = *(const float4*)&sRB[rcur][1][k0 + 4];
            u32x4 ap;
            {
                const f32x2 z0 = pk_fma(xv2, mk2(wA.x, wA.y), mk2(bA.x, bA.y));
                const f32x2 z1 = pk_fma(xv2, mk2(wA.z, wA.w), mk2(bA.z, bA.w));
                const f32x2 z2 = pk_fma(xv2, mk2(wB.x, wB.y), mk2(bB.x, bB.y));
                const f32x2 z3 = pk_fma(xv2, mk2(wB.z, wB.w), mk2(bB.z, bB.w));
                ap[0] = cvtpk_bf16(felu(z0.x), felu(z0.y));
                ap[1] = cvtpk_bf16(felu(z1.x), felu(z1.y));
                ap[2] = cvtpk_bf16(felu(z2.x), felu(z2.y));
                ap[3] = cvtpk_bf16(felu(z3.x), felu(z3.y));
            }

            // -- issue stage for phase p+2 into ring slot (cur+2)%3 --
            {
                const int nxt2 = (cur == 0) ? 2 : cur - 1;   // (cur+2)%3
                if (ks < 6) {
                    STAGE_B(vbase + vi, ks + 2, nxt2);
                } else if (vi < 7) {
                    STAGE_B(vbase + vi + 1, ks - 6, nxt2);
                    if (ks == 6) STAGE_ROWS(vbase + vi + 1, rcur ^ 1);
                }
            }

            // -- MFMA: 16 col-frags, B read in-loop from sB[cur] --
            const short8 af = __builtin_bit_cast(short8, ap);
            const char* bb = (const char*)sB[cur] + rdbase;
            __builtin_amdgcn_s_setprio(1);
#pragma unroll
            for (int f = 0; f < 16; ++f) {
                const short8 bf = __builtin_bit_cast(short8, *(const u32x4*)(bb + (f << 10)));
                acc[f] = __builtin_amdgcn_mfma_f32_16x16x32_bf16(af, bf, acc[f], 0, 0, 0);
            }
            __builtin_amdgcn_s_setprio(0);
            cur = (cur == 2) ? 0 : cur + 1;
        }

        // -- epilogue (pk-f32 pairs): gate/skip + wave-local LN + weighted acc --
        float xr[4], wv_[4];
#pragma unroll
        for (int r = 0; r < 4; ++r) {
            const int tl = wid * 16 + kg * 4 + r;
            xr[r]  = sX[tl][vi];
            wv_[r] = sW[tl][vi];
        }
        const f32x2 xr01 = {xr[0], xr[1]}, xr23 = {xr[2], xr[3]};
        f32x2 ps01 = {0.f, 0.f}, ps23 = {0.f, 0.f};
        f32x2 pq01 = {0.f, 0.f}, pq23 = {0.f, 0.f};
#pragma unroll
        for (int f = 0; f < 16; ++f) {
            const int h = f * 16 + c;
            const float Wg_ = sRB[rcur][2][h], bg_ = sRB[rcur][3][h];  // pre-scaled
            const float Ws_ = sRB[rcur][4][h], bs_ = sRB[rcur][5][h];
            const float b2_ = sRB[rcur][6][h];
            const f32x2 Wgp = {Wg_, Wg_}, bgp = {bg_, bg_};
            const f32x2 Wsp = {Ws_, Ws_}, bsp = {bs_, bs_}, b2p = {b2_, b2_};
            const f32x2 a01 = {acc[f][0], acc[f][1]};
            const f32x2 a23 = {acc[f][2], acc[f][3]};
            const f32x2 zg01 = pk_fma(xr01, Wgp, bgp);
            const f32x2 zg23 = pk_fma(xr23, Wgp, bgp);
            const f32x2 e01 = {exp2f(zg01.x), exp2f(zg01.y)};
            const f32x2 e23 = {exp2f(zg23.x), exp2f(zg23.y)};
            const f32x2 d01 = pk_add(e01, one2);
            const f32x2 d23 = pk_add(e23, one2);
            const f32x2 s01 = {__builtin_amdgcn_rcpf(d01.x), __builtin_amdgcn_rcpf(d01.y)};
            const f32x2 s23 = {__builtin_amdgcn_rcpf(d23.x), __builtin_amdgcn_rcpf(d23.y)};
            const f32x2 R01 = pk_add(a01, b2p);
            const f32x2 R23 = pk_add(a23, b2p);
            const f32x2 sk01 = pk_fma(xr01, Wsp, bsp);
            const f32x2 sk23 = pk_fma(xr23, Wsp, bsp);
            const f32x2 y01 = pk_fma(s01, R01, sk01);
            const f32x2 y23 = pk_fma(s23, R23, sk23);
            ps01 = pk_add(ps01, y01);
            ps23 = pk_add(ps23, y23);
            pq01 = pk_fma(y01, y01, pq01);
            pq23 = pk_fma(y23, y23, pq23);
            acc[f][0] = y01.x; acc[f][1] = y01.y;
            acc[f][2] = y23.x; acc[f][3] = y23.y;
        }
        float ps[4] = {ps01.x, ps01.y, ps23.x, ps23.y};
        float pq[4] = {pq01.x, pq01.y, pq23.x, pq23.y};
#pragma unroll
        for (int m = 1; m <= 8; m <<= 1)
#pragma unroll
            for (int r = 0; r < 4; ++r) {
                ps[r] += __shfl_xor(ps[r], m);
                pq[r] += __shfl_xor(pq[r], m);
            }
        float nmu[4], wiv[4];
#pragma unroll
        for (int r = 0; r < 4; ++r) {
            const float mu = ps[r] * (1.0f / 256.0f);
            const float vr = fmaf(-mu, mu, pq[r] * (1.0f / 256.0f));
            nmu[r] = -mu;
            wiv[r] = wv_[r] * rsqrtf(vr + LN_EPS);
        }
        const f32x2 nmu01 = {nmu[0], nmu[1]}, nmu23 = {nmu[2], nmu[3]};
        const f32x2 wiv01 = {wiv[0], wiv[1]}, wiv23 = {wiv[2], wiv[3]};
        const f32x2 wv01 = {wv_[0], wv_[1]}, wv23 = {wv_[2], wv_[3]};
#pragma unroll
        for (int f = 0; f < 16; ++f) {
            const int h = f * 16 + c;
            const float gv_ = sRB[rcur][7][h], bev_ = sRB[rcur][8][h];
            const f32x2 gvp = {gv_, gv_}, bevp = {bev_, bev_};
            f32x2 w01 = {wacc[f][0], wacc[f][1]};
            f32x2 w23 = {wacc[f][2], wacc[f][3]};
            const f32x2 y01 = {acc[f][0], acc[f][1]};
            const f32x2 y23 = {acc[f][2], acc[f][3]};
            const f32x2 t01 = pk_mul(pk_add(y01, nmu01), wiv01);
            const f32x2 t23 = pk_mul(pk_add(y23, nmu23), wiv23);
            w01 = pk_fma(t01, gvp, pk_fma(wv01, bevp, w01));
            w23 = pk_fma(t23, gvp, pk_fma(wv23, bevp, w23));
            wacc[f][0] = w01.x; wacc[f][1] = w01.y;
            wacc[f][2] = w23.x; wacc[f][3] = w23.y;
        }
    }
#undef STAGE_B
#undef STAGE_ROWS

    // -- write per-vgroup partials (bf16) --
    const int tokb = t0 + wid * 16 + kg * 4;
    if (partials16) {
        unsigned short* P = partials16 + (size_t)vg * NTOK * NH;
#pragma unroll
        for (int r = 0; r < 4; ++r) {
            unsigned short* rowp = P + (size_t)(tokb + r) * NH + c;
#pragma unroll
            for (int f = 0; f < 16; ++f) rowp[f * 16] = f32_to_bf16(wacc[f][r]);
        }
    } else {
#pragma unroll
        for (int r = 0; r < 4; ++r) {
            float* rowp = outacc + (size_t)(tokb + r) * NH + c;
#pragma unroll
            for (int f = 0; f < 16; ++f) atomicAdd(&rowp[f * 16], wacc[f][r]);
        }
    }
}

// ---------------- Kernel D: sum the 8 bf16 vgroup partials -> f32 out -------------
__global__ __launch_bounds__(256) void k_reduce16(const unsigned short* __restrict__ P,
                                                  float* __restrict__ out) {
    const size_t i2 = (size_t)blockIdx.x * 256 + threadIdx.x;   // pair index
    float lo = 0.0f, hi = 0.0f;
#pragma unroll
    for (int sl = 0; sl < 8; ++sl) {
        const uint32_t u = ((const uint32_t*)(P + (size_t)sl * (NTOK * NH)))[i2];
        lo += __builtin_bit_cast(float, u << 16);
        hi += __builtin_bit_cast(float, u & 0xFFFF0000u);
    }
    ((float2*)out)[i2] = float2{lo, hi};
}

extern "C" void kernel_launch(void* const* d_in, const int* in_sizes, int n_in,
                              void* d_out, int out_size, void* d_ws, size_t ws_size,
                              hipStream_t stream) {
    const float* x   = (const float*)d_in[0];
    const float* W1  = (const float*)d_in[1];
    const float* b1  = (const float*)d_in[2];
    const float* W2  = (const float*)d_in[3];
    const float* b2  = (const float*)d_in[4];
    const float* Wg  = (const float*)d_in[5];
    const float* bg  = (const float*)d_in[6];
    const float* Ws  = (const float*)d_in[7];
    const float* bs  = (const float*)d_in[8];
    const float* g1  = (const float*)d_in[9];
    const float* be1 = (const float*)d_in[10];
    const float* nW1 = (const float*)d_in[11];
    const float* nb1 = (const float*)d_in[12];
    const float* nW2 = (const float*)d_in[13];
    const float* nb2 = (const float*)d_in[14];
    const float* nWg = (const float*)d_in[15];
    const float* nbg = (const float*)d_in[16];
    const float* ng  = (const float*)d_in[17];
    const float* nbe = (const float*)d_in[18];
    float* out = (float*)d_out;

    // ws: [0,1M) wgt | [1M,9M) W2T | [9M,+64K) Wg2 | [+64K,+128K) bg2 |
    //     [10M,26M) partials16 (bf16)
    char* ws = (char*)d_ws;
    float* ws_wgt = (float*)ws;
    unsigned short* ws_W2T = (unsigned short*)(ws + (1 << 20));
    float* ws_Wg2 = (float*)(ws + (9 << 20));
    float* ws_bg2 = (float*)(ws + (9 << 20) + (64 << 10));
    const size_t part_off = (size_t)10 << 20;
    const size_t part_bytes = (size_t)8 * NTOK * NH * 2;   // bf16
    const bool use_part = ws_size >= part_off + part_bytes;
    unsigned short* ws_part = use_part ? (unsigned short*)(ws + part_off) : nullptr;

    k_pre<<<dim3(4096 + NTOK / 4 + 16), dim3(256), 0, stream>>>(
        W2, ws_W2T, x, nW1, nb1, nW2, nb2, nWg, nbg, ng, nbe, ws_wgt,
        Wg, bg, ws_Wg2, ws_bg2);
    if (!use_part) hipMemsetAsync(d_out, 0, (size_t)out_size * 4, stream);
    k_main<<<dim3(512), dim3(256), 0, stream>>>(x, ws_W2T, W1, b1, ws_Wg2, ws_bg2,
                                                Ws, bs, b2, g1, be1, ws_wgt,
                                                ws_part, out);
    if (use_part)
        k_reduce16<<<dim3(NTOK * NH / 2 / 256), dim3(256), 0, stream>>>(ws_part, out);
}

// Round 18
// 126.053 us; speedup vs baseline: 1.0367x; 1.0367x over previous
//
#include <hip/hip_runtime.h>
#include <hip/hip_bf16.h>
#include <stdint.h>

// VSN: B=16,T=256 -> NTOK=4096 tokens, V=64 vars, H=256 hidden.
#define NTOK 4096
#define NV 64
#define NH 256
#define LN_EPS 1e-5f

typedef __attribute__((ext_vector_type(8))) short short8;
typedef __attribute__((ext_vector_type(4))) float f32x4;
typedef __attribute__((ext_vector_type(2))) float f32x2;   // true vector: safe in asm "v"
typedef __attribute__((ext_vector_type(4))) uint32_t u32x4;

__device__ __forceinline__ f32x2 mk2(float a, float b) {
    f32x2 r; r.x = a; r.y = b; return r;
}
__device__ __forceinline__ unsigned short f32_to_bf16(float f) {
    uint32_t u = __builtin_bit_cast(uint32_t, f);
    return (unsigned short)((u + 0x7FFFu + ((u >> 16) & 1u)) >> 16);  // RNE
}
__device__ __forceinline__ float fsigmoid(float z) { return 1.0f / (1.0f + __expf(-z)); }
__device__ __forceinline__ float felu(float z) { return z > 0.0f ? z : (__expf(z) - 1.0f); }
// packed f32 dual-rate math (VOP3P, CDNA3+) on genuine ext-vector pairs
__device__ __forceinline__ f32x2 pk_fma(f32x2 a, f32x2 b, f32x2 c) {
    f32x2 d;
    asm("v_pk_fma_f32 %0, %1, %2, %3" : "=v"(d) : "v"(a), "v"(b), "v"(c));
    return d;
}
__device__ __forceinline__ f32x2 pk_add(f32x2 a, f32x2 b) {
    f32x2 d;
    asm("v_pk_add_f32 %0, %1, %2" : "=v"(d) : "v"(a), "v"(b));
    return d;
}
__device__ __forceinline__ f32x2 pk_mul(f32x2 a, f32x2 b) {
    f32x2 d;
    asm("v_pk_mul_f32 %0, %1, %2" : "=v"(d) : "v"(a), "v"(b));
    return d;
}
__device__ __forceinline__ uint32_t cvtpk_bf16(float lo, float hi) {
    uint32_t r;
    asm("v_cvt_pk_bf16_f32 %0, %1, %2" : "=v"(r) : "v"(lo), "v"(hi));
    return r;
}
__device__ __forceinline__ void gload16(const void* g, void* l) {
    __builtin_amdgcn_global_load_lds(
        (const __attribute__((address_space(1))) uint32_t*)g,
        (__attribute__((address_space(3))) uint32_t*)l, 16, 0, 0);
}

// ---------------- Kernel A: W2 [v][h][o] f32 -> W2T [v][o][h] bf16 ----------------
__global__ __launch_bounds__(256) void k_w2t(const float* __restrict__ W2,
                                             unsigned short* __restrict__ W2T) {
    __shared__ float tile[32][33];
    const int v  = blockIdx.x >> 6;
    const int t  = blockIdx.x & 63;
    const int h0 = (t & 7) * 32;
    const int o0 = (t >> 3) * 32;
    const int r  = threadIdx.x >> 3;
    const int c4 = (threadIdx.x & 7) * 4;
    const float4 d = *(const float4*)(W2 + ((size_t)v * NH + h0 + r) * NH + o0 + c4);
    tile[r][c4 + 0] = d.x; tile[r][c4 + 1] = d.y;
    tile[r][c4 + 2] = d.z; tile[r][c4 + 3] = d.w;
    __syncthreads();
    ushort4 o;
    o.x = f32_to_bf16(tile[c4 + 0][r]);
    o.y = f32_to_bf16(tile[c4 + 1][r]);
    o.z = f32_to_bf16(tile[c4 + 2][r]);
    o.w = f32_to_bf16(tile[c4 + 3][r]);
    *(ushort4*)(W2T + ((size_t)v * NH + o0 + r) * NH + h0 + c4) = o;
}

// ---------------- Kernel B: weight-network GRN + softmax (+ fused Wg/bg scale) ----
__global__ __launch_bounds__(256) void k_weights(
    const float* __restrict__ x,
    const float* __restrict__ nW1, const float* __restrict__ nb1,
    const float* __restrict__ nW2, const float* __restrict__ nb2,
    const float* __restrict__ nWg, const float* __restrict__ nbg,
    const float* __restrict__ ng,  const float* __restrict__ nbe,
    float* __restrict__ wout_buf,
    const float* __restrict__ Wg, const float* __restrict__ bg,
    float* __restrict__ Wg2, float* __restrict__ bg2) {
    if (blockIdx.x >= NTOK / 4) {
        const int i = (blockIdx.x - NTOK / 4) * 256 + threadIdx.x;  // 4096 float4s
        const float cc = -1.44269504f;
        const float4 a = ((const float4*)Wg)[i];
        const float4 b = ((const float4*)bg)[i];
        ((float4*)Wg2)[i] = float4{a.x * cc, a.y * cc, a.z * cc, a.w * cc};
        ((float4*)bg2)[i] = float4{b.x * cc, b.y * cc, b.z * cc, b.w * cc};
        return;
    }
    const int wv = threadIdx.x >> 6;
    const int lane = threadIdx.x & 63;
    const int tok = blockIdx.x * 4 + wv;
    const float xv = x[(size_t)tok * NV + lane];
    float acc1 = nb1[lane], accg = nbg[lane];
#pragma unroll 8
    for (int k = 0; k < 64; ++k) {
        const float xk = __shfl(xv, k);
        acc1 = fmaf(xk, nW1[k * 64 + lane], acc1);
        accg = fmaf(xk, nWg[k * 64 + lane], accg);
    }
    const float h  = felu(acc1);
    const float wg = fsigmoid(accg);
    float acc2 = nb2[lane];
#pragma unroll 8
    for (int k = 0; k < 64; ++k) {
        const float hk = __shfl(h, k);
        acc2 = fmaf(hk, nW2[k * 64 + lane], acc2);
    }
    const float pre = xv + wg * acc2;
    float s = pre;
#pragma unroll
    for (int m = 32; m >= 1; m >>= 1) s += __shfl_xor(s, m);
    const float mu = s * (1.0f / 64.0f);
    const float dd = pre - mu;
    float s2 = dd * dd;
#pragma unroll
    for (int m = 32; m >= 1; m >>= 1) s2 += __shfl_xor(s2, m);
    const float inv = rsqrtf(s2 * (1.0f / 64.0f) + LN_EPS);
    const float wln = dd * inv * ng[lane] + nbe[lane];
    float mx = wln;
#pragma unroll
    for (int m = 32; m >= 1; m >>= 1) mx = fmaxf(mx, __shfl_xor(mx, m));
    const float e = __expf(wln - mx);
    float se = e;
#pragma unroll
    for (int m = 32; m >= 1; m >>= 1) se += __shfl_xor(se, m);
    wout_buf[(size_t)tok * NV + lane] = e / se;
}

__device__ __forceinline__ const float* row_ptr(int r, const float* W1, const float* b1,
                                                const float* Wg, const float* bg,
                                                const float* Ws, const float* bs,
                                                const float* b2, const float* g1,
                                                const float* be1) {
    switch (r) {
        case 0: return W1; case 1: return b1; case 2: return Wg; case 3: return bg;
        case 4: return Ws; case 5: return bs; case 6: return b2; case 7: return g1;
        default: return be1;
    }
}

// ---------------- Kernel C: best-passing structure (r15) --------------------------
// grid 512 (bid&7 = vgroup/XCD; bid>>3 = 64-token tile). 256 thr = 4 waves; each
// wave = 16 tokens x ALL 256 cols. Per-phase sync: s_waitcnt vmcnt(4) + raw
// s_barrier (3-buf B ring staged 2 phases ahead). Arithmetic: v_pk_* on f32x2
// ext-vectors, exp2-native sigmoid (pre-scaled Wg2/bg2), v_cvt_pk_bf16 A-pack.
// Tail: partials stored as bf16 (halves partial-path HBM traffic).
__global__ __launch_bounds__(256, 2) void k_main(
    const float* __restrict__ x, const unsigned short* __restrict__ W2T,
    const float* __restrict__ W1, const float* __restrict__ b1,
    const float* __restrict__ Wg2, const float* __restrict__ bg2,
    const float* __restrict__ Ws, const float* __restrict__ bs,
    const float* __restrict__ b2, const float* __restrict__ g1,
    const float* __restrict__ be1, const float* __restrict__ wgts,
    unsigned short* __restrict__ partials16,  // [8][NTOK][NH] bf16 or nullptr
    float* __restrict__ outacc) {             // atomic fallback
    __shared__ u32x4 sB[3][1024];     // 3 x 16KB B K-step panel ring, slot-swizzled
    __shared__ float sRB[2][9][256];  // 2 x {W1,b1,Wg2,bg2,Ws,bs,b2,g1,be1}
    __shared__ float sX[64][9];       // [tok][var] (+pad)
    __shared__ float sW[64][9];

    const int tid  = threadIdx.x;
    const int wid  = tid >> 6, lane = tid & 63;  // wid = token-group
    const int c    = lane & 15, kg = lane >> 4;
    const int bid  = blockIdx.x;
    const int vg   = bid & 7, tt = bid >> 3;
    const int t0   = tt * 64, vbase = vg * 8;

    const float* r0p = row_ptr(2 * wid,     W1, b1, Wg2, bg2, Ws, bs, b2, g1, be1);
    const float* r1p = row_ptr(2 * wid + 1, W1, b1, Wg2, bg2, Ws, bs, b2, g1, be1);

    // per-thread B-stage constants (4 chunks): idx -> (o, slot) -> src/dst offsets
    int bsrc[4], bdst[4];
#pragma unroll
    for (int q = 0; q < 4; ++q) {
        const int idx = wid * 256 + q * 64 + lane;
        const int o = idx >> 2, sl = idx & 3;
        const int s = (sl - (o >> 1)) & 3;
        bsrc[q] = o * NH + s * 8;   // element offset within the var's W2T
        bdst[q] = idx * 16;         // byte offset within panel
    }

#define STAGE_B(vt, kt, buf)                                                     \
    do {                                                                         \
        const unsigned short* Wsrc_ = W2T + (size_t)(vt) * (NH * NH) + (kt) * 32;\
        char* dst_ = (char*)sB[buf];                                             \
        gload16(Wsrc_ + bsrc[0], dst_ + bdst[0]);                                \
        gload16(Wsrc_ + bsrc[1], dst_ + bdst[1]);                                \
        gload16(Wsrc_ + bsrc[2], dst_ + bdst[2]);                                \
        gload16(Wsrc_ + bsrc[3], dst_ + bdst[3]);                                \
    } while (0)

#define STAGE_ROWS(vt, rbuf)                                                     \
    do {                                                                         \
        gload16(r0p + (size_t)(vt) * NH + lane * 4,                              \
                (char*)sRB[rbuf] + (2 * wid) * 1024);                            \
        gload16(r1p + (size_t)(vt) * NH + lane * 4,                              \
                (char*)sRB[rbuf] + (2 * wid + 1) * 1024);                        \
        if (wid == 0)                                                            \
            gload16(be1 + (size_t)(vt) * NH + lane * 4,                          \
                    (char*)sRB[rbuf] + 8 * 1024);                                \
    } while (0)

    // ---- prologue: stage (v0,ks0)->sB0, (v0,ks1)->sB1, rows v0; fill sX/sW ----
    STAGE_B(vbase, 0, 0);
    STAGE_B(vbase, 1, 1);
    STAGE_ROWS(vbase, 0);
#pragma unroll
    for (int e = 0; e < 2; ++e) {
        const int ee = tid + e * 256;
        const int row = ee >> 3, cc = ee & 7;
        sX[row][cc] = x[(size_t)(t0 + row) * NV + vbase + cc];
        sW[row][cc] = wgts[(size_t)(t0 + row) * NV + vbase + cc];
    }
    __syncthreads();   // one full drain (prologue only)

    // b128 B-frag read base: row o = f*16+c, slot rotated -> balanced banks
    const int rdbase = c * 64 + (((kg + (c >> 1)) & 3) << 4);
    const f32x4 fzero = {0.f, 0.f, 0.f, 0.f};
    const f32x2 one2 = {1.0f, 1.0f};

    f32x4 wacc[16];
#pragma unroll
    for (int f = 0; f < 16; ++f) wacc[f] = fzero;

    int cur = 0;   // sB ring position for the phase being consumed

#pragma unroll 1
    for (int vi = 0; vi < 8; ++vi) {
        const int rcur = vi & 1;
        const float xv = sX[wid * 16 + c][vi];
        const f32x2 xv2 = {xv, xv};

        f32x4 acc[16];
#pragma unroll
        for (int f = 0; f < 16; ++f) acc[f] = fzero;

#pragma unroll 1
        for (int ks = 0; ks < 8; ++ks) {
            // ---- phase top: counted wait + raw barrier (no vmcnt(0) drain) ----
            asm volatile("s_waitcnt vmcnt(4)" ::: "memory");
            __builtin_amdgcn_sched_barrier(0);
            __builtin_amdgcn_s_barrier();

            // -- A-frag gen (one 16x32 tile per wave): pk-fma pairs + cvt_pk --
            const int k0 = ks * 32 + kg * 8;
            const float4 wA = *(const float4*)&sRB[rcur][0][k0];
            const float4 wB = *(const float4*)&sRB[rcur][0][k0 + 4];
            const float4 bA = *(const float4*)&sRB[rcur][1][k0];
            const float4 bB = *(const float4*)&sRB[rcur][1][k0 + 4];
            u32x4 ap;
            {
                const f32x2 z0 = pk_fma(xv2, mk2(wA.x, wA.y), mk2(bA.x, bA.y));
                const f32x2 z1 = pk_fma(xv2, mk2(wA.z, wA.w), mk2(bA.z, bA.w));
                const f32x2 z2 = pk_fma(xv2, mk2(wB.x, wB.y), mk2(bB.x, bB.y));
                const f32x2 z3 = pk_fma(xv2, mk2(wB.z, wB.w), mk2(bB.z, bB.w));
                ap[0] = cvtpk_bf16(felu(z0.x), felu(z0.y));
                ap[1] = cvtpk_bf16(felu(z1.x), felu(z1.y));
                ap[2] = cvtpk_bf16(felu(z2.x), felu(z2.y));
                ap[3] = cvtpk_bf16(felu(z3.x), felu(z3.y));
            }

            // -- issue stage for phase p+2 into ring slot (cur+2)%3 --
            {
                const int nxt2 = (cur == 0) ? 2 : cur - 1;   // (cur+2)%3
                if (ks < 6) {
                    STAGE_B(vbase + vi, ks + 2, nxt2);
                } else if (vi < 7) {
                    STAGE_B(vbase + vi + 1, ks - 6, nxt2);
                    if (ks == 6) STAGE_ROWS(vbase + vi + 1, rcur ^ 1);
                }
            }

            // -- MFMA: 16 col-frags, B read in-loop from sB[cur] --
            const short8 af = __builtin_bit_cast(short8, ap);
            const char* bb = (const char*)sB[cur] + rdbase;
            __builtin_amdgcn_s_setprio(1);
#pragma unroll
            for (int f = 0; f < 16; ++f) {
                const short8 bf = __builtin_bit_cast(short8, *(const u32x4*)(bb + (f << 10)));
                acc[f] = __builtin_amdgcn_mfma_f32_16x16x32_bf16(af, bf, acc[f], 0, 0, 0);
            }
            __builtin_amdgcn_s_setprio(0);
            cur = (cur == 2) ? 0 : cur + 1;
        }

        // -- epilogue (pk-f32 pairs): gate/skip + wave-local LN + weighted acc --
        float xr[4], wv_[4];
#pragma unroll
        for (int r = 0; r < 4; ++r) {
            const int tl = wid * 16 + kg * 4 + r;
            xr[r]  = sX[tl][vi];
            wv_[r] = sW[tl][vi];
        }
        const f32x2 xr01 = {xr[0], xr[1]}, xr23 = {xr[2], xr[3]};
        f32x2 ps01 = {0.f, 0.f}, ps23 = {0.f, 0.f};
        f32x2 pq01 = {0.f, 0.f}, pq23 = {0.f, 0.f};
#pragma unroll
        for (int f = 0; f < 16; ++f) {
            const int h = f * 16 + c;
            const float Wg_ = sRB[rcur][2][h], bg_ = sRB[rcur][3][h];  // pre-scaled
            const float Ws_ = sRB[rcur][4][h], bs_ = sRB[rcur][5][h];
            const float b2_ = sRB[rcur][6][h];
            const f32x2 Wgp = {Wg_, Wg_}, bgp = {bg_, bg_};
            const f32x2 Wsp = {Ws_, Ws_}, bsp = {bs_, bs_}, b2p = {b2_, b2_};
            const f32x2 a01 = {acc[f][0], acc[f][1]};
            const f32x2 a23 = {acc[f][2], acc[f][3]};
            const f32x2 zg01 = pk_fma(xr01, Wgp, bgp);
            const f32x2 zg23 = pk_fma(xr23, Wgp, bgp);
            const f32x2 e01 = {exp2f(zg01.x), exp2f(zg01.y)};
            const f32x2 e23 = {exp2f(zg23.x), exp2f(zg23.y)};
            const f32x2 d01 = pk_add(e01, one2);
            const f32x2 d23 = pk_add(e23, one2);
            const f32x2 s01 = {__builtin_amdgcn_rcpf(d01.x), __builtin_amdgcn_rcpf(d01.y)};
            const f32x2 s23 = {__builtin_amdgcn_rcpf(d23.x), __builtin_amdgcn_rcpf(d23.y)};
            const f32x2 R01 = pk_add(a01, b2p);
            const f32x2 R23 = pk_add(a23, b2p);
            const f32x2 sk01 = pk_fma(xr01, Wsp, bsp);
            const f32x2 sk23 = pk_fma(xr23, Wsp, bsp);
            const f32x2 y01 = pk_fma(s01, R01, sk01);
            const f32x2 y23 = pk_fma(s23, R23, sk23);
            ps01 = pk_add(ps01, y01);
            ps23 = pk_add(ps23, y23);
            pq01 = pk_fma(y01, y01, pq01);
            pq23 = pk_fma(y23, y23, pq23);
            acc[f][0] = y01.x; acc[f][1] = y01.y;
            acc[f][2] = y23.x; acc[f][3] = y23.y;
        }
        float ps[4] = {ps01.x, ps01.y, ps23.x, ps23.y};
        float pq[4] = {pq01.x, pq01.y, pq23.x, pq23.y};
#pragma unroll
        for (int m = 1; m <= 8; m <<= 1)
#pragma unroll
            for (int r = 0; r < 4; ++r) {
                ps[r] += __shfl_xor(ps[r], m);
                pq[r] += __shfl_xor(pq[r], m);
            }
        float nmu[4], wiv[4];
#pragma unroll
        for (int r = 0; r < 4; ++r) {
            const float mu = ps[r] * (1.0f / 256.0f);
            const float vr = fmaf(-mu, mu, pq[r] * (1.0f / 256.0f));
            nmu[r] = -mu;
            wiv[r] = wv_[r] * rsqrtf(vr + LN_EPS);
        }
        const f32x2 nmu01 = {nmu[0], nmu[1]}, nmu23 = {nmu[2], nmu[3]};
        const f32x2 wiv01 = {wiv[0], wiv[1]}, wiv23 = {wiv[2], wiv[3]};
        const f32x2 wv01 = {wv_[0], wv_[1]}, wv23 = {wv_[2], wv_[3]};
#pragma unroll
        for (int f = 0; f < 16; ++f) {
            const int h = f * 16 + c;
            const float gv_ = sRB[rcur][7][h], bev_ = sRB[rcur][8][h];
            const f32x2 gvp = {gv_, gv_}, bevp = {bev_, bev_};
            f32x2 w01 = {wacc[f][0], wacc[f][1]};
            f32x2 w23 = {wacc[f][2], wacc[f][3]};
            const f32x2 y01 = {acc[f][0], acc[f][1]};
            const f32x2 y23 = {acc[f][2], acc[f][3]};
            const f32x2 t01 = pk_mul(pk_add(y01, nmu01), wiv01);
            const f32x2 t23 = pk_mul(pk_add(y23, nmu23), wiv23);
            w01 = pk_fma(t01, gvp, pk_fma(wv01, bevp, w01));
            w23 = pk_fma(t23, gvp, pk_fma(wv23, bevp, w23));
            wacc[f][0] = w01.x; wacc[f][1] = w01.y;
            wacc[f][2] = w23.x; wacc[f][3] = w23.y;
        }
    }
#undef STAGE_B
#undef STAGE_ROWS

    // -- write per-vgroup partials (bf16) --
    const int tokb = t0 + wid * 16 + kg * 4;
    if (partials16) {
        unsigned short* P = partials16 + (size_t)vg * NTOK * NH;
#pragma unroll
        for (int r = 0; r < 4; ++r) {
            unsigned short* rowp = P + (size_t)(tokb + r) * NH + c;
#pragma unroll
            for (int f = 0; f < 16; ++f) rowp[f * 16] = f32_to_bf16(wacc[f][r]);
        }
    } else {
#pragma unroll
        for (int r = 0; r < 4; ++r) {
            float* rowp = outacc + (size_t)(tokb + r) * NH + c;
#pragma unroll
            for (int f = 0; f < 16; ++f) atomicAdd(&rowp[f * 16], wacc[f][r]);
        }
    }
}

// ---------------- Kernel D: sum the 8 bf16 vgroup partials -> f32 out -------------
__global__ __launch_bounds__(256) void k_reduce16(const unsigned short* __restrict__ P,
                                                  float* __restrict__ out) {
    const size_t i2 = (size_t)blockIdx.x * 256 + threadIdx.x;   // pair index
    float lo = 0.0f, hi = 0.0f;
#pragma unroll
    for (int sl = 0; sl < 8; ++sl) {
        const uint32_t u = ((const uint32_t*)(P + (size_t)sl * (NTOK * NH)))[i2];
        lo += __builtin_bit_cast(float, u << 16);
        hi += __builtin_bit_cast(float, u & 0xFFFF0000u);
    }
    ((float2*)out)[i2] = float2{lo, hi};
}

extern "C" void kernel_launch(void* const* d_in, const int* in_sizes, int n_in,
                              void* d_out, int out_size, void* d_ws, size_t ws_size,
                              hipStream_t stream) {
    const float* x   = (const float*)d_in[0];
    const float* W1  = (const float*)d_in[1];
    const float* b1  = (const float*)d_in[2];
    const float* W2  = (const float*)d_in[3];
    const float* b2  = (const float*)d_in[4];
    const float* Wg  = (const float*)d_in[5];
    const float* bg  = (const float*)d_in[6];
    const float* Ws  = (const float*)d_in[7];
    const float* bs  = (const float*)d_in[8];
    const float* g1  = (const float*)d_in[9];
    const float* be1 = (const float*)d_in[10];
    const float* nW1 = (const float*)d_in[11];
    const float* nb1 = (const float*)d_in[12];
    const float* nW2 = (const float*)d_in[13];
    const float* nb2 = (const float*)d_in[14];
    const float* nWg = (const float*)d_in[15];
    const float* nbg = (const float*)d_in[16];
    const float* ng  = (const float*)d_in[17];
    const float* nbe = (const float*)d_in[18];
    float* out = (float*)d_out;

    // ws: [0,1M) wgt | [1M,9M) W2T | [9M,+64K) Wg2 | [+64K,+128K) bg2 |
    //     [10M,26M) partials16 (bf16)
    char* ws = (char*)d_ws;
    float* ws_wgt = (float*)ws;
    unsigned short* ws_W2T = (unsigned short*)(ws + (1 << 20));
    float* ws_Wg2 = (float*)(ws + (9 << 20));
    float* ws_bg2 = (float*)(ws + (9 << 20) + (64 << 10));
    const size_t part_off = (size_t)10 << 20;
    const size_t part_bytes = (size_t)8 * NTOK * NH * 2;   // bf16
    const bool use_part = ws_size >= part_off + part_bytes;
    unsigned short* ws_part = use_part ? (unsigned short*)(ws + part_off) : nullptr;

    k_w2t<<<dim3(64 * 64), dim3(256), 0, stream>>>(W2, ws_W2T);
    k_weights<<<dim3(NTOK / 4 + 16), dim3(256), 0, stream>>>(
        x, nW1, nb1, nW2, nb2, nWg, nbg, ng, nbe, ws_wgt, Wg, bg, ws_Wg2, ws_bg2);
    if (!use_part) hipMemsetAsync(d_out, 0, (size_t)out_size * 4, stream);
    k_main<<<dim3(512), dim3(256), 0, stream>>>(x, ws_W2T, W1, b1, ws_Wg2, ws_bg2,
                                                Ws, bs, b2, g1, be1, ws_wgt,
                                                ws_part, out);
    if (use_part)
        k_reduce16<<<dim3(NTOK * NH / 2 / 256), dim3(256), 0, stream>>>(ws_part, out);
}